// Round 1
// baseline (70.445 us; speedup 1.0000x reference)
//
#include <hip/hip_runtime.h>
#include <hip/hip_bf16.h>

// Problem constants
#define DM    1024          // d_model
#define NH    2             // heads
#define IDX   32            // idx dim per head
#define HQ    (NH*IDX)      // 64 query cols
#define TT    4096          // tokens per batch
#define BB    2             // batch
#define RR    (BB*TT)       // 8192 total rows
#define NC    112           // padded projection cols (64 Q + 32 K + 2 w + 14 pad)

typedef short  s16x8 __attribute__((ext_vector_type(8)));
typedef float  f32x4 __attribute__((ext_vector_type(4)));

// round-to-nearest-even fp32 -> bf16 bits
__device__ __forceinline__ unsigned short f2bf(float f) {
    unsigned int u = __builtin_bit_cast(unsigned int, f);
    u += 0x7FFFu + ((u >> 16) & 1u);
    return (unsigned short)(u >> 16);
}

// ---------------------------------------------------------------------------
// Kernel 1: pack Wq|Wk|Ww into transposed bf16 WcatT[NC][DM]
// ---------------------------------------------------------------------------
__global__ __launch_bounds__(256) void prep_wcat(const float* __restrict__ Wq,
                                                 const float* __restrict__ Wk,
                                                 const float* __restrict__ Ww,
                                                 unsigned short* __restrict__ WcatT) {
    int idx = blockIdx.x * 256 + threadIdx.x;        // NC*DM total
    int j = idx >> 10;                               // col  (0..111)
    int i = idx & 1023;                              // k    (0..1023)
    float v = 0.f;
    if (j < 64)       v = Wq[i * HQ + j];
    else if (j < 96)  v = Wk[i * IDX + (j - 64)];
    else if (j < 98)  v = Ww[i * NH + (j - 96)];
    WcatT[j * DM + i] = f2bf(v);
}

// ---------------------------------------------------------------------------
// Kernel 2: projections. grid = 512 stripes (16 rows each), 7 waves/block,
// each wave computes one 16x16 tile of x @ Wcat over K=1024.
// ---------------------------------------------------------------------------
__global__ __launch_bounds__(448) void proj_kernel(const float* __restrict__ x,
                                                   const unsigned short* __restrict__ WcatT,
                                                   unsigned short* __restrict__ Qb,
                                                   unsigned short* __restrict__ Kb,
                                                   float* __restrict__ wb) {
    const int r0   = blockIdx.x * 16;
    const int wave = threadIdx.x >> 6;   // N-tile 0..6
    const int lane = threadIdx.x & 63;
    const int lrow = lane & 15;
    const int lseg = lane >> 4;

    f32x4 acc = {0.f, 0.f, 0.f, 0.f};
    const float*          xr = x + (size_t)(r0 + lrow) * DM + lseg * 8;
    const unsigned short* wr = WcatT + (size_t)(wave * 16 + lrow) * DM + lseg * 8;

    #pragma unroll 4
    for (int kc = 0; kc < DM; kc += 32) {
        float4 a0 = *(const float4*)(xr + kc);
        float4 a1 = *(const float4*)(xr + kc + 4);
        s16x8 af;
        af[0] = (short)f2bf(a0.x); af[1] = (short)f2bf(a0.y);
        af[2] = (short)f2bf(a0.z); af[3] = (short)f2bf(a0.w);
        af[4] = (short)f2bf(a1.x); af[5] = (short)f2bf(a1.y);
        af[6] = (short)f2bf(a1.z); af[7] = (short)f2bf(a1.w);
        s16x8 bfv = *(const s16x8*)(wr + kc);
        acc = __builtin_amdgcn_mfma_f32_16x16x32_bf16(af, bfv, acc, 0, 0, 0);
    }

    const int col = wave * 16 + lrow;
    #pragma unroll
    for (int r = 0; r < 4; ++r) {
        int row = r0 + lseg * 4 + r;
        float v = acc[r];
        if (col < 64)       Qb[(size_t)row * HQ + col]        = f2bf(v);
        else if (col < 96)  Kb[(size_t)row * IDX + (col - 64)] = f2bf(v);
        else if (col < 98)  wb[(size_t)row * NH + (col - 96)]  = v;
    }
}

// ---------------------------------------------------------------------------
// Kernel 3: scores. Each wave: one 16-row t-stripe x 512-col s-chunk.
// Per 16x16 s-tile: 1 K-fragment load, 2 MFMAs (one per head), relu+weight,
// coalesced fp32 store.
// ---------------------------------------------------------------------------
__global__ __launch_bounds__(256) void score_kernel(const unsigned short* __restrict__ Qb,
                                                    const unsigned short* __restrict__ Kb,
                                                    const float* __restrict__ wb,
                                                    float* __restrict__ out) {
    const int rb   = blockIdx.x >> 3;    // 0..127 row-block (64 rows)
    const int sc   = blockIdx.x & 7;     // 0..7  s-chunk (512 cols)
    const int wave = threadIdx.x >> 6;
    const int lane = threadIdx.x & 63;
    const int lrow = lane & 15;
    const int lseg = lane >> 4;

    const int t0 = rb * 64 + wave * 16;          // global row in [0,8192)
    const int b  = t0 >> 12;                     // batch

    const unsigned short* qrow = Qb + (size_t)(t0 + lrow) * HQ + lseg * 8;
    s16x8 qa0 = *(const s16x8*)(qrow);           // head 0, k = 8*lseg..+8
    s16x8 qa1 = *(const s16x8*)(qrow + IDX);     // head 1

    float2 wpair[4];
    #pragma unroll
    for (int r = 0; r < 4; ++r)
        wpair[r] = *(const float2*)(wb + (size_t)(t0 + lseg * 4 + r) * NH);

    const unsigned short* kbase =
        Kb + ((size_t)(b * TT) + sc * 512 + lrow) * IDX + lseg * 8;
    float* obase = out + (size_t)(t0 + lseg * 4) * TT + sc * 512 + lrow;

    const f32x4 zero = {0.f, 0.f, 0.f, 0.f};

    #pragma unroll 4
    for (int it = 0; it < 32; ++it) {
        s16x8 kb = *(const s16x8*)(kbase + (size_t)it * 16 * IDX);
        f32x4 d0 = __builtin_amdgcn_mfma_f32_16x16x32_bf16(qa0, kb, zero, 0, 0, 0);
        f32x4 d1 = __builtin_amdgcn_mfma_f32_16x16x32_bf16(qa1, kb, zero, 0, 0, 0);
        #pragma unroll
        for (int r = 0; r < 4; ++r) {
            float v = wpair[r].x * fmaxf(d0[r], 0.f)
                    + wpair[r].y * fmaxf(d1[r], 0.f);
            obase[(size_t)r * TT + it * 16] = v;
        }
    }
}

// ---------------------------------------------------------------------------
extern "C" void kernel_launch(void* const* d_in, const int* in_sizes, int n_in,
                              void* d_out, int out_size, void* d_ws, size_t ws_size,
                              hipStream_t stream) {
    const float* x  = (const float*)d_in[0];
    const float* Wq = (const float*)d_in[1];
    const float* Wk = (const float*)d_in[2];
    const float* Ww = (const float*)d_in[3];
    float* out = (float*)d_out;

    // workspace layout (16B aligned)
    char* ws = (char*)d_ws;
    unsigned short* WcatT = (unsigned short*)ws;                    // NC*DM*2   = 229376
    unsigned short* Qb    = (unsigned short*)(ws + 256 * 1024);     // RR*HQ*2   = 1 MB
    unsigned short* Kb    = (unsigned short*)(ws + 256 * 1024 + 1024 * 1024);  // RR*IDX*2 = 512 KB
    float*          wb    = (float*)(ws + 256 * 1024 + 1024 * 1024 + 512 * 1024); // RR*NH*4 = 64 KB

    hipLaunchKernelGGL(prep_wcat, dim3((NC * DM) / 256), dim3(256), 0, stream,
                       Wq, Wk, Ww, WcatT);
    hipLaunchKernelGGL(proj_kernel, dim3(RR / 16), dim3(448), 0, stream,
                       x, WcatT, Qb, Kb, wb);
    hipLaunchKernelGGL(score_kernel, dim3((RR / 64) * 8), dim3(256), 0, stream,
                       Qb, Kb, wb, out);
}

// Round 2
// 51.913 us; speedup vs baseline: 1.3570x; 1.3570x over previous
//
#include <hip/hip_runtime.h>
#include <hip/hip_bf16.h>

// Problem constants
#define DM    1024          // d_model
#define NH    2             // heads
#define IDX   32            // idx dim per head
#define HQ    (NH*IDX)      // 64 query cols
#define TT    4096          // tokens per batch
#define BB    2             // batch
#define RR    (BB*TT)       // 8192 total rows
#define NC    112           // padded projection cols (64 Q + 32 K + 2 w + 14 pad)
#define NTIL  7             // NC/16

typedef short  s16x8 __attribute__((ext_vector_type(8)));
typedef float  f32x4 __attribute__((ext_vector_type(4)));

// round-to-nearest-even fp32 -> bf16 bits
__device__ __forceinline__ unsigned short f2bf(float f) {
    unsigned int u = __builtin_bit_cast(unsigned int, f);
    u += 0x7FFFu + ((u >> 16) & 1u);
    return (unsigned short)(u >> 16);
}

// ---------------------------------------------------------------------------
// Kernel 1: pack Wq|Wk|Ww into transposed bf16 WcatT[NC][DM]
// ---------------------------------------------------------------------------
__global__ __launch_bounds__(256) void prep_wcat(const float* __restrict__ Wq,
                                                 const float* __restrict__ Wk,
                                                 const float* __restrict__ Ww,
                                                 unsigned short* __restrict__ WcatT) {
    int idx = blockIdx.x * 256 + threadIdx.x;        // NC*DM total
    int j = idx >> 10;                               // col  (0..111)
    int i = idx & 1023;                              // k    (0..1023)
    float v = 0.f;
    if (j < 64)       v = Wq[i * HQ + j];
    else if (j < 96)  v = Wk[i * IDX + (j - 64)];
    else if (j < 98)  v = Ww[i * NH + (j - 96)];
    WcatT[j * DM + i] = f2bf(v);
}

// ---------------------------------------------------------------------------
// Kernel 2: projections, x read/converted ONCE per stripe.
// Block = 256 threads = 4 waves = 2 stripes x 2 K-halves.
// Each wave: one 16-row stripe, K-half of 512, all 7 col-tiles in acc[7].
// K-halves reduced through LDS; khalf==0 wave does the epilogue.
// ---------------------------------------------------------------------------
__global__ __launch_bounds__(256) void proj_kernel(const float* __restrict__ x,
                                                   const unsigned short* __restrict__ WcatT,
                                                   unsigned short* __restrict__ Qb,
                                                   unsigned short* __restrict__ Kb,
                                                   float* __restrict__ wb) {
    __shared__ float red[2][NTIL][64][4];            // 28672 B

    const int wave  = threadIdx.x >> 6;              // 0..3
    const int lane  = threadIdx.x & 63;
    const int sl    = wave >> 1;                     // stripe within block
    const int khalf = wave & 1;
    const int stripe = blockIdx.x * 2 + sl;          // 0..511
    const int r0    = stripe * 16;
    const int lrow  = lane & 15;
    const int lseg  = lane >> 4;

    f32x4 acc[NTIL] = {};

    const float*          xr = x + (size_t)(r0 + lrow) * DM + khalf * 512 + lseg * 8;
    const unsigned short* wr = WcatT + (size_t)lrow * DM + khalf * 512 + lseg * 8;

    #pragma unroll 2
    for (int kc = 0; kc < 512; kc += 32) {
        float4 a0 = *(const float4*)(xr + kc);
        float4 a1 = *(const float4*)(xr + kc + 4);
        s16x8 af;
        af[0] = (short)f2bf(a0.x); af[1] = (short)f2bf(a0.y);
        af[2] = (short)f2bf(a0.z); af[3] = (short)f2bf(a0.w);
        af[4] = (short)f2bf(a1.x); af[5] = (short)f2bf(a1.y);
        af[6] = (short)f2bf(a1.z); af[7] = (short)f2bf(a1.w);
        #pragma unroll
        for (int t = 0; t < NTIL; ++t) {
            s16x8 bfv = *(const s16x8*)(wr + (size_t)t * 16 * DM + kc);
            acc[t] = __builtin_amdgcn_mfma_f32_16x16x32_bf16(af, bfv, acc[t], 0, 0, 0);
        }
    }

    if (khalf == 1) {
        #pragma unroll
        for (int t = 0; t < NTIL; ++t)
            *(f32x4*)&red[sl][t][lane][0] = acc[t];
    }
    __syncthreads();
    if (khalf == 0) {
        #pragma unroll
        for (int t = 0; t < NTIL; ++t) {
            acc[t] += *(const f32x4*)&red[sl][t][lane][0];
            const int col = t * 16 + lrow;
            #pragma unroll
            for (int r = 0; r < 4; ++r) {
                int row = r0 + lseg * 4 + r;
                float v = acc[t][r];
                if (col < 64)       Qb[(size_t)row * HQ + col]         = f2bf(v);
                else if (col < 96)  Kb[(size_t)row * IDX + (col - 64)] = f2bf(v);
                else if (col < 98)  wb[(size_t)row * NH + (col - 96)]  = v;
            }
        }
    }
}

// ---------------------------------------------------------------------------
// Kernel 3: scores. Each wave: one 16-row t-stripe x 512-col s-chunk.
// Per 16x16 s-tile: 1 K-fragment load, 2 MFMAs (one per head), relu+weight,
// coalesced fp32 store.
// ---------------------------------------------------------------------------
__global__ __launch_bounds__(256) void score_kernel(const unsigned short* __restrict__ Qb,
                                                    const unsigned short* __restrict__ Kb,
                                                    const float* __restrict__ wb,
                                                    float* __restrict__ out) {
    const int rb   = blockIdx.x >> 3;    // 0..127 row-block (64 rows)
    const int sc   = blockIdx.x & 7;     // 0..7  s-chunk (512 cols)
    const int wave = threadIdx.x >> 6;
    const int lane = threadIdx.x & 63;
    const int lrow = lane & 15;
    const int lseg = lane >> 4;

    const int t0 = rb * 64 + wave * 16;          // global row in [0,8192)
    const int b  = t0 >> 12;                     // batch

    const unsigned short* qrow = Qb + (size_t)(t0 + lrow) * HQ + lseg * 8;
    s16x8 qa0 = *(const s16x8*)(qrow);           // head 0, k = 8*lseg..+8
    s16x8 qa1 = *(const s16x8*)(qrow + IDX);     // head 1

    float2 wpair[4];
    #pragma unroll
    for (int r = 0; r < 4; ++r)
        wpair[r] = *(const float2*)(wb + (size_t)(t0 + lseg * 4 + r) * NH);

    const unsigned short* kbase =
        Kb + ((size_t)(b * TT) + sc * 512 + lrow) * IDX + lseg * 8;
    float* obase = out + (size_t)(t0 + lseg * 4) * TT + sc * 512 + lrow;

    const f32x4 zero = {0.f, 0.f, 0.f, 0.f};

    #pragma unroll 4
    for (int it = 0; it < 32; ++it) {
        s16x8 kb = *(const s16x8*)(kbase + (size_t)it * 16 * IDX);
        f32x4 d0 = __builtin_amdgcn_mfma_f32_16x16x32_bf16(qa0, kb, zero, 0, 0, 0);
        f32x4 d1 = __builtin_amdgcn_mfma_f32_16x16x32_bf16(qa1, kb, zero, 0, 0, 0);
        #pragma unroll
        for (int r = 0; r < 4; ++r) {
            float v = wpair[r].x * fmaxf(d0[r], 0.f)
                    + wpair[r].y * fmaxf(d1[r], 0.f);
            obase[(size_t)r * TT + it * 16] = v;
        }
    }
}

// ---------------------------------------------------------------------------
extern "C" void kernel_launch(void* const* d_in, const int* in_sizes, int n_in,
                              void* d_out, int out_size, void* d_ws, size_t ws_size,
                              hipStream_t stream) {
    const float* x  = (const float*)d_in[0];
    const float* Wq = (const float*)d_in[1];
    const float* Wk = (const float*)d_in[2];
    const float* Ww = (const float*)d_in[3];
    float* out = (float*)d_out;

    // workspace layout (16B aligned)
    char* ws = (char*)d_ws;
    unsigned short* WcatT = (unsigned short*)ws;                    // NC*DM*2   = 229376
    unsigned short* Qb    = (unsigned short*)(ws + 256 * 1024);     // RR*HQ*2   = 1 MB
    unsigned short* Kb    = (unsigned short*)(ws + 256 * 1024 + 1024 * 1024);  // RR*IDX*2 = 512 KB
    float*          wb    = (float*)(ws + 256 * 1024 + 1024 * 1024 + 512 * 1024); // RR*NH*4 = 64 KB

    hipLaunchKernelGGL(prep_wcat, dim3((NC * DM) / 256), dim3(256), 0, stream,
                       Wq, Wk, Ww, WcatT);
    hipLaunchKernelGGL(proj_kernel, dim3(RR / 32), dim3(256), 0, stream,
                       x, WcatT, Qb, Kb, wb);
    hipLaunchKernelGGL(score_kernel, dim3((RR / 64) * 8), dim3(256), 0, stream,
                       Qb, Kb, wb, out);
}